// Round 3
// baseline (972.646 us; speedup 1.0000x reference)
//
#include <hip/hip_runtime.h>

#define BB 2048
#define IMG 784
#define HWD 28
#define C1 32
#define C2 64
#define PP 169
#define PD 13
#define F3 10816
#define N3 2048
#define K3W 169
#define K4W 32
#define NOUT 10
#define CONV 27          // pooled-used conv2 output region is 27x27
#define CHUNK 16         // ocs per conv2pool phase
#define SCR_STRIDE 736   // 729 padded

__device__ __forceinline__ float ap2mag(float c) {
    // 2^round(log2(max(|c|,1e-38)))  (round half to even, like jnp.round)
    float a = fmaxf(fabsf(c), 1e-38f);
    return exp2f(rintf(log2f(a)));
}

// ---------------- conv1 (fp32 x, binarized weights) ----------------
// Thread layout: ch = tid&31, slice = tid>>5; 9 weights hoisted to named registers
// (NO private arrays -> no scratch spill; spill was the R1 700us pathology).
__global__ void conv1_stats(const float* __restrict__ x, const float* __restrict__ w1,
                            const float* __restrict__ cb1, const float* __restrict__ meanIn,
                            double* __restrict__ outSum, int pass) {
    __shared__ float xs[IMG];
    __shared__ float ws[C1 * 9];
    __shared__ float red[256];
    int n = blockIdx.x, tid = threadIdx.x;
    for (int i = tid; i < IMG; i += 256) xs[i] = x[n * IMG + i];
    for (int i = tid; i < C1 * 9; i += 256) ws[i] = (w1[i] >= 0.f) ? 1.f : -1.f;
    __syncthreads();
    int ch = tid & 31, slice = tid >> 5;
    float b = cb1[ch];
    float m = pass ? meanIn[ch] : 0.f;
    float k0 = ws[ch * 9 + 0], k1 = ws[ch * 9 + 1], k2 = ws[ch * 9 + 2];
    float k3 = ws[ch * 9 + 3], k4 = ws[ch * 9 + 4], k5 = ws[ch * 9 + 5];
    float k6 = ws[ch * 9 + 6], k7 = ws[ch * 9 + 7], k8 = ws[ch * 9 + 8];
    float acc = 0.f;
    for (int p = slice; p < IMG; p += 8) {
        int py = p / HWD, px = p - py * HWD;
        bool tp = py > 0, bo = py < HWD - 1, lf = px > 0, rt = px < HWD - 1;
        const float* c0 = &xs[p];
        float s = c0[0] * k4;
        if (tp) {
            s += c0[-HWD] * k1;
            if (lf) s += c0[-HWD - 1] * k0;
            if (rt) s += c0[-HWD + 1] * k2;
        }
        if (lf) s += c0[-1] * k3;
        if (rt) s += c0[1] * k5;
        if (bo) {
            s += c0[HWD] * k7;
            if (lf) s += c0[HWD - 1] * k6;
            if (rt) s += c0[HWD + 1] * k8;
        }
        float v = fmaxf(s + b, 0.f);
        if (pass == 0) acc += v;
        else { float c = v - m; acc += fabsf(c) * ap2mag(c); }
    }
    red[tid] = acc;
    __syncthreads();
    if (tid < C1) {
        float t = 0.f;
        for (int sl = 0; sl < 8; sl++) t += red[sl * 32 + tid];
        atomicAdd(&outSum[tid], (double)t);
    }
}

// binarize(shift_bn(relu(conv1))) -> 32 channel bits packed per pixel via __ballot.
__global__ void conv1_pack(const float* __restrict__ x, const float* __restrict__ w1,
                           const float* __restrict__ cb1, const float* __restrict__ mean1,
                           const float* __restrict__ scale1, const float* __restrict__ beta1,
                           unsigned int* __restrict__ s1p) {
    __shared__ float xs[IMG];
    __shared__ float ws[C1 * 9];
    __shared__ unsigned int pbits[IMG];
    int n = blockIdx.x, tid = threadIdx.x;
    for (int i = tid; i < IMG; i += 256) xs[i] = x[n * IMG + i];
    for (int i = tid; i < C1 * 9; i += 256) ws[i] = (w1[i] >= 0.f) ? 1.f : -1.f;
    __syncthreads();
    int ch = tid & 31, slice = tid >> 5;
    float b = cb1[ch];
    float m = mean1[ch];
    float sc = scale1[ch];
    float bt = beta1[ch];
    float k0 = ws[ch * 9 + 0], k1 = ws[ch * 9 + 1], k2 = ws[ch * 9 + 2];
    float k3 = ws[ch * 9 + 3], k4 = ws[ch * 9 + 4], k5 = ws[ch * 9 + 5];
    float k6 = ws[ch * 9 + 6], k7 = ws[ch * 9 + 7], k8 = ws[ch * 9 + 8];
    int half = tid & 63;  // 0 or 32 writes
    for (int p = slice; p < IMG; p += 8) {
        int py = p / HWD, px = p - py * HWD;
        bool tp = py > 0, bo = py < HWD - 1, lf = px > 0, rt = px < HWD - 1;
        const float* c0 = &xs[p];
        float s = c0[0] * k4;
        if (tp) {
            s += c0[-HWD] * k1;
            if (lf) s += c0[-HWD - 1] * k0;
            if (rt) s += c0[-HWD + 1] * k2;
        }
        if (lf) s += c0[-1] * k3;
        if (rt) s += c0[1] * k5;
        if (bo) {
            s += c0[HWD] * k7;
            if (lf) s += c0[HWD - 1] * k6;
            if (rt) s += c0[HWD + 1] * k8;
        }
        float v = fmaxf(s + b, 0.f);
        float val = sc * (v - m) + bt;
        unsigned long long mask = __ballot(val >= 0.f);
        if (half == 0) pbits[p] = (unsigned int)mask;
        else if (half == 32) pbits[p] = (unsigned int)(mask >> 32);
    }
    __syncthreads();
    for (int i = tid; i < IMG; i += 256) s1p[n * IMG + i] = pbits[i];
}

// ---------------- conv2 weight packing ----------------
__global__ void pack_w2(const float* __restrict__ w2, unsigned int* __restrict__ w2p) {
    int t = blockIdx.x * blockDim.x + threadIdx.x;
    if (t >= C2 * 9) return;
    int oc = t / 9, k = t % 9;
    unsigned int bits = 0;
    for (int ic = 0; ic < C1; ic++)
        bits |= (w2[oc * 288 + ic * 9 + k] >= 0.f ? 1u : 0u) << ic;
    w2p[t] = bits;
}

// ---------------- fused conv2 + maxpool3s2, two-phase ----------------
// Phase A: conv over the 27x27 pooled-used region for CHUNK ocs into LDS scratch
// (lane = consecutive pixel -> stride-1 banks, conflict-free; each conv pixel
// computed ONCE vs 1.83x redundancy of pool-window recompute).
// Phase B: 3x3 stride-2 max over scratch, write pre-bias int16.
__global__ __launch_bounds__(256) void conv2pool(const unsigned int* __restrict__ s1p,
                                                 const unsigned int* __restrict__ w2p,
                                                 short* __restrict__ p2i) {
    __shared__ unsigned int ss[IMG];
    __shared__ unsigned int wp[C2 * 9];
    __shared__ short scr[CHUNK * SCR_STRIDE];
    int n = blockIdx.x, tid = threadIdx.x;
    for (int i = tid; i < IMG; i += 256) ss[i] = s1p[n * IMG + i];
    for (int i = tid; i < C2 * 9; i += 256) wp[i] = w2p[i];
    __syncthreads();
    for (int base = 0; base < C2; base += CHUNK) {
        for (int ol = 0; ol < CHUNK; ol++) {
            int oc = base + ol;
            unsigned int w0 = wp[oc * 9 + 0], w1 = wp[oc * 9 + 1], w2 = wp[oc * 9 + 2];
            unsigned int w3 = wp[oc * 9 + 3], w4 = wp[oc * 9 + 4], w5 = wp[oc * 9 + 5];
            unsigned int w6 = wp[oc * 9 + 6], w7 = wp[oc * 9 + 7], w8 = wp[oc * 9 + 8];
            for (int p = tid; p < CONV * CONV; p += 256) {
                int y = p / CONV, xx = p - y * CONV;
                // conv pixel (y,xx), y,xx in [0,27): only top row / left col clip
                const unsigned int* c = &ss[y * HWD + xx];
                bool tp = y > 0, lf = xx > 0;
                int s = 0, cnt = 0;
                if (tp) {
                    if (lf) { s += __popc(c[-HWD - 1] ^ w0); cnt += 32; }
                    s += __popc(c[-HWD] ^ w1); cnt += 32;
                    s += __popc(c[-HWD + 1] ^ w2); cnt += 32;
                }
                if (lf) { s += __popc(c[-1] ^ w3); cnt += 32; }
                s += __popc(c[0] ^ w4); cnt += 32;
                s += __popc(c[1] ^ w5); cnt += 32;
                if (lf) { s += __popc(c[HWD - 1] ^ w6); cnt += 32; }
                s += __popc(c[HWD] ^ w7); cnt += 32;
                s += __popc(c[HWD + 1] ^ w8); cnt += 32;
                scr[ol * SCR_STRIDE + p] = (short)(cnt - 2 * s);
            }
        }
        __syncthreads();
        for (int q = tid; q < CHUNK * PP; q += 256) {
            int ol = q / PP, pix = q - ol * PP;
            int py = pix / PD, px = pix - py * PD;
            const short* r = &scr[ol * SCR_STRIDE + (2 * py) * CONV + 2 * px];
            int m0 = max(max((int)r[0], (int)r[1]), (int)r[2]);
            int m1 = max(max((int)r[CONV], (int)r[CONV + 1]), (int)r[CONV + 2]);
            int m2 = max(max((int)r[2 * CONV], (int)r[2 * CONV + 1]), (int)r[2 * CONV + 2]);
            p2i[n * F3 + (base + ol) * PP + pix] = (short)max(max(m0, m1), m2);
        }
        __syncthreads();
    }
}

// ---------------- stats over pooled layer-2 ----------------
__global__ void p2_stats(const short* __restrict__ p2i, const float* __restrict__ cb2,
                         const float* __restrict__ meanIn, double* __restrict__ outSum, int pass) {
    __shared__ float red[256];
    int n = blockIdx.x, tid = threadIdx.x;
    int ch = tid & 63, slice = tid >> 6;
    float b = cb2[ch];
    float m = pass ? meanIn[ch] : 0.f;
    float acc = 0.f;
    const short* row = p2i + n * F3 + ch * PP;
    for (int p = slice; p < PP; p += 4) {
        float v = fmaxf((float)row[p] + b, 0.f);
        if (pass == 0) acc += v;
        else { float c = v - m; acc += fabsf(c) * ap2mag(c); }
    }
    red[tid] = acc;
    __syncthreads();
    if (tid < C2) {
        float t = 0.f;
        for (int sl = 0; sl < 4; sl++) t += red[sl * 64 + tid];
        atomicAdd(&outSum[tid], (double)t);
    }
}

// binarize layer-2 -> packed u64 rows; grid-stride over wave-words (fat blocks,
// few workgroups: tiny-wave dispatch overhead was a suspected hidden cost).
__global__ void p2_pack(const short* __restrict__ p2i, const float* __restrict__ cb2,
                        const float* __restrict__ mean2, const float* __restrict__ scale2,
                        const float* __restrict__ beta2, unsigned long long* __restrict__ hp3) {
    int lane = threadIdx.x & 63;
    int wid = (blockIdx.x * blockDim.x + threadIdx.x) >> 6;
    int nw = (gridDim.x * blockDim.x) >> 6;
    for (int w = wid; w < BB * K3W; w += nw) {
        int n = w / K3W, j = w - n * K3W;
        int f = j * 64 + lane;
        int oc = f / PP;
        float v = fmaxf((float)p2i[n * F3 + f] + cb2[oc], 0.f);
        float val = scale2[oc] * (v - mean2[oc]) + beta2[oc];
        unsigned long long mask = __ballot(val >= 0.f);
        if (lane == 0) hp3[w] = mask;
    }
}

__global__ void w3_pack(const float* __restrict__ w3, unsigned long long* __restrict__ wp3) {
    int lane = threadIdx.x & 63;
    int wid = (blockIdx.x * blockDim.x + threadIdx.x) >> 6;
    int nw = (gridDim.x * blockDim.x) >> 6;
    for (int w = wid; w < N3 * K3W; w += nw) {
        int nn = w / K3W, j = w - nn * K3W;
        float wv = w3[(size_t)nn * F3 + j * 64 + lane];
        unsigned long long mask = __ballot(wv >= 0.f);
        if (lane == 0) wp3[w] = mask;
    }
}

// ---------------- lin3: XNOR-popcount GEMM, 64x64 tile, 4x4 per thread ----------------
__global__ __launch_bounds__(256) void lin3_gemm(const unsigned long long* __restrict__ hp3,
                                                 const unsigned long long* __restrict__ wp3,
                                                 const float* __restrict__ b3l,
                                                 float* __restrict__ h3) {
    __shared__ unsigned long long aT[64][9];
    __shared__ unsigned long long bT[64][9];
    int tx = threadIdx.x & 15, ty = threadIdx.x >> 4;
    int m0 = blockIdx.y * 64, n0 = blockIdx.x * 64;
    int s[4][4];
#pragma unroll
    for (int i = 0; i < 4; i++)
#pragma unroll
        for (int j = 0; j < 4; j++) s[i][j] = 0;
    for (int k0 = 0; k0 < K3W; k0 += 8) {
        for (int t = threadIdx.x; t < 512; t += 256) {
            int r = t >> 3, kk = t & 7;
            int k = k0 + kk;
            aT[r][kk] = (k < K3W) ? hp3[(m0 + r) * K3W + k] : 0ULL;
            bT[r][kk] = (k < K3W) ? wp3[(n0 + r) * K3W + k] : 0ULL;
        }
        __syncthreads();
#pragma unroll
        for (int kk = 0; kk < 8; kk++) {
            unsigned long long a[4], b[4];
#pragma unroll
            for (int i = 0; i < 4; i++) a[i] = aT[ty * 4 + i][kk];
#pragma unroll
            for (int j = 0; j < 4; j++) b[j] = bT[tx * 4 + j][kk];
#pragma unroll
            for (int i = 0; i < 4; i++)
#pragma unroll
                for (int j = 0; j < 4; j++) s[i][j] += __popcll(a[i] ^ b[j]);
        }
        __syncthreads();
    }
#pragma unroll
    for (int i = 0; i < 4; i++) {
        int m = m0 + ty * 4 + i;
#pragma unroll
        for (int j = 0; j < 4; j++) {
            int nn = n0 + tx * 4 + j;
            float v = fmaxf((float)(F3 - 2 * s[i][j]) + b3l[nn], 0.f);
            h3[(size_t)m * N3 + nn] = v;
        }
    }
}

// ---------------- stats over h3 (per feature, across batch) ----------------
__global__ void h3_stats(const float* __restrict__ h3, const float* __restrict__ meanIn,
                         double* __restrict__ outSum, int pass) {
    int nn = blockIdx.x * 256 + threadIdx.x;
    int m0 = blockIdx.y * 128;
    float m = pass ? meanIn[nn] : 0.f;
    float acc = 0.f;
    for (int mm = m0; mm < m0 + 128; mm++) {
        float v = h3[(size_t)mm * N3 + nn];
        if (pass == 0) acc += v;
        else { float c = v - m; acc += fabsf(c) * ap2mag(c); }
    }
    atomicAdd(&outSum[nn], (double)acc);
}

__global__ void h3_pack(const float* __restrict__ h3, const float* __restrict__ mean3,
                        const float* __restrict__ scale3, const float* __restrict__ beta3,
                        unsigned long long* __restrict__ h4p) {
    int lane = threadIdx.x & 63;
    int wid = (blockIdx.x * blockDim.x + threadIdx.x) >> 6;
    int nw = (gridDim.x * blockDim.x) >> 6;
    for (int w = wid; w < BB * K4W; w += nw) {
        int m = w / K4W, j = w - m * K4W;
        int f = j * 64 + lane;
        float v = h3[(size_t)m * N3 + f];
        float val = scale3[f] * (v - mean3[f]) + beta3[f];
        unsigned long long mask = __ballot(val >= 0.f);
        if (lane == 0) h4p[w] = mask;
    }
}

__global__ void w4_pack(const float* __restrict__ w4, unsigned long long* __restrict__ wp4) {
    int gw = (blockIdx.x * blockDim.x + threadIdx.x) >> 6;
    int lane = threadIdx.x & 63;
    if (gw >= NOUT * K4W) return;
    int o = gw / K4W, j = gw % K4W;
    float w = w4[o * N3 + j * 64 + lane];
    unsigned long long mask = __ballot(w >= 0.f);
    if (lane == 0) wp4[o * K4W + j] = mask;
}

// one thread per (m,o); weights in LDS with stride 33 (pad: stride 32 u64 would
// put all o at the same bank pair -> 10-way conflict)
__global__ __launch_bounds__(256) void lin4_out(const unsigned long long* __restrict__ h4p,
                                                const unsigned long long* __restrict__ wp4,
                                                const float* __restrict__ b4,
                                                float* __restrict__ out) {
    __shared__ unsigned long long w[NOUT * 33];
    int tid = threadIdx.x;
    for (int i = tid; i < NOUT * K4W; i += 256) w[(i / K4W) * 33 + (i % K4W)] = wp4[i];
    __syncthreads();
    int g = blockIdx.x * 256 + tid;  // 80 blocks * 256 = 20480 exactly
    int m = g / NOUT, o = g - m * NOUT;
    const unsigned long long* h = &h4p[(size_t)m * K4W];
    int c = 0;
#pragma unroll
    for (int k = 0; k < K4W; k++) c += __popcll(h[k] ^ w[o * 33 + k]);
    out[g] = (float)(N3 - 2 * c) + b4[o];
}

// ---------------- small finalize kernels ----------------
__global__ void finalize_mean(const double* __restrict__ sumd, float* __restrict__ meanOut,
                              int n, double count) {
    int i = blockIdx.x * blockDim.x + threadIdx.x;
    if (i < n) meanOut[i] = (float)(sumd[i] / count);
}

__global__ void finalize_scale(const double* __restrict__ vard, const float* __restrict__ g,
                               float* __restrict__ scaleOut, int n, double count) {
    int i = blockIdx.x * blockDim.x + threadIdx.x;
    if (i >= n) return;
    float var = (float)(vard[i] / count);
    float t = var + 1e-4f;
    float inv = 1.0f / sqrtf(t);
    double p = exp2(rint(log2((double)inv)));
    float gg = g[i];
    float ap2g;
    if (gg == 0.f) ap2g = 0.f;
    else {
        double ag = fabs((double)gg);
        if (ag < 1e-38) ag = 1e-38;
        ap2g = (float)exp2(rint(log2(ag)));
        if (gg < 0.f) ap2g = -ap2g;
    }
    scaleOut[i] = ap2g * (float)p;
}

extern "C" void kernel_launch(void* const* d_in, const int* in_sizes, int n_in,
                              void* d_out, int out_size, void* d_ws, size_t ws_size,
                              hipStream_t stream) {
    const float* x   = (const float*)d_in[0];
    const float* w1  = (const float*)d_in[1];
    const float* cb1 = (const float*)d_in[2];
    const float* g1  = (const float*)d_in[3];
    const float* bt1 = (const float*)d_in[4];
    const float* w2  = (const float*)d_in[5];
    const float* cb2 = (const float*)d_in[6];
    const float* g2  = (const float*)d_in[7];
    const float* bt2 = (const float*)d_in[8];
    const float* w3  = (const float*)d_in[9];
    const float* b3l = (const float*)d_in[10];
    const float* g3  = (const float*)d_in[11];
    const float* bt3 = (const float*)d_in[12];
    const float* w4  = (const float*)d_in[13];
    const float* b4l = (const float*)d_in[14];
    float* out = (float*)d_out;

    char* base = (char*)d_ws;
    size_t off = 0;
    auto carve = [&](size_t bytes) { char* p = base + off; off = (off + bytes + 255) & ~(size_t)255; return p; };
    unsigned int* s1p       = (unsigned int*)carve((size_t)BB * IMG * 4);
    short* p2i              = (short*)carve((size_t)BB * C2 * PP * 2);
    unsigned long long* hp3 = (unsigned long long*)carve((size_t)BB * K3W * 8);
    unsigned long long* wp3 = (unsigned long long*)carve((size_t)N3 * K3W * 8);
    float* h3               = (float*)carve((size_t)BB * N3 * 4);
    unsigned long long* h4p = (unsigned long long*)carve((size_t)BB * K4W * 8);
    unsigned long long* wp4 = (unsigned long long*)carve((size_t)NOUT * K4W * 8);
    unsigned int* w2p       = (unsigned int*)carve((size_t)C2 * 9 * 4);
    double* sums            = (double*)carve((size_t)(32 + 32 + 64 + 64 + 2048 + 2048) * 8);
    double* sum1d = sums;        // 32
    double* var1d = sums + 32;   // 32
    double* sum2d = sums + 64;   // 64
    double* var2d = sums + 128;  // 64
    double* sum3d = sums + 192;  // 2048
    double* var3d = sums + 2240; // 2048
    float* fstats           = (float*)carve((size_t)(32 + 32 + 64 + 64 + 2048 + 2048) * 4);
    float* mean1 = fstats;          float* scale1 = fstats + 32;
    float* mean2 = fstats + 64;     float* scale2 = fstats + 128;
    float* mean3 = fstats + 192;    float* scale3 = fstats + 2240;

    hipMemsetAsync(sums, 0, (size_t)(32 + 32 + 64 + 64 + 2048 + 2048) * 8, stream);

    // layer 1
    conv1_stats<<<BB, 256, 0, stream>>>(x, w1, cb1, mean1, sum1d, 0);
    finalize_mean<<<1, 64, 0, stream>>>(sum1d, mean1, 32, (double)BB * IMG);
    conv1_stats<<<BB, 256, 0, stream>>>(x, w1, cb1, mean1, var1d, 1);
    finalize_scale<<<1, 64, 0, stream>>>(var1d, g1, scale1, 32, (double)BB * IMG);
    conv1_pack<<<BB, 256, 0, stream>>>(x, w1, cb1, mean1, scale1, bt1, s1p);

    // layer 2
    pack_w2<<<1, 576, 0, stream>>>(w2, w2p);
    conv2pool<<<BB, 256, 0, stream>>>(s1p, w2p, p2i);
    p2_stats<<<BB, 256, 0, stream>>>(p2i, cb2, mean2, sum2d, 0);
    finalize_mean<<<1, 64, 0, stream>>>(sum2d, mean2, 64, (double)BB * PP);
    p2_stats<<<BB, 256, 0, stream>>>(p2i, cb2, mean2, var2d, 1);
    finalize_scale<<<1, 64, 0, stream>>>(var2d, g2, scale2, 64, (double)BB * PP);
    p2_pack<<<1024, 256, 0, stream>>>(p2i, cb2, mean2, scale2, bt2, hp3);

    // lin3
    w3_pack<<<2048, 256, 0, stream>>>(w3, wp3);
    lin3_gemm<<<dim3(32, 32), 256, 0, stream>>>(hp3, wp3, b3l, h3);
    h3_stats<<<dim3(8, 16), 256, 0, stream>>>(h3, mean3, sum3d, 0);
    finalize_mean<<<8, 256, 0, stream>>>(sum3d, mean3, 2048, (double)BB);
    h3_stats<<<dim3(8, 16), 256, 0, stream>>>(h3, mean3, var3d, 1);
    finalize_scale<<<8, 256, 0, stream>>>(var3d, g3, scale3, 2048, (double)BB);
    h3_pack<<<256, 256, 0, stream>>>(h3, mean3, scale3, bt3, h4p);

    // lin4
    w4_pack<<<(NOUT * K4W + 3) / 4, 256, 0, stream>>>(w4, wp4);
    lin4_out<<<80, 256, 0, stream>>>(h4p, wp4, b4l, out);

    (void)in_sizes; (void)n_in; (void)out_size; (void)ws_size;
}